// Round 1
// baseline (44.126 us; speedup 1.0000x reference)
//
#include <hip/hip_runtime.h>
#include <math.h>

#define BATCH   128     // rows per block
#define STRIDE  33      // 32 + 1 pad -> conflict-free LDS
#define NBINS   1024

__global__ __launch_bounds__(128, 2) void hist_kernel(const float* __restrict__ act,
                                                      float* __restrict__ gC,
                                                      int rows)
{
    __shared__ float Phi_s[BATCH * STRIDE];
    __shared__ float Plo_s[BATCH * STRIDE];
    __shared__ float C_lds[NBINS];

    const int tid = threadIdx.x;

    // zero the block-level C accumulator (covered by the barrier below)
    #pragma unroll
    for (int k = 0; k < NBINS / BATCH; ++k)
        C_lds[tid + k * BATCH] = 0.0f;

    const int row = blockIdx.x * BATCH + tid;

    float v[10];
    float valid = 1.0f;
    if (row < rows) {
        const float* a = act + (size_t)row * 10;
        #pragma unroll
        for (int k = 0; k < 10; ++k) v[k] = a[k];
    } else {
        valid = 0.0f;
        #pragma unroll
        for (int k = 0; k < 10; ++k) v[k] = 0.0f;
    }

    // Product trees. Index bit order: r=0 is the MSB of the 10-bit joint index
    // (matches the reference's idx = old*2 + new_bit recursion).
    // hi covers r=0..4, lo covers r=5..9; joint idx = hi*32 + lo.
    float hi[32], lo[32];
    {
        float t2[2], t4[4], t8[8], t16[16];
        t2[0] = valid * (1.0f - v[0]); t2[1] = valid * v[0];
        #pragma unroll
        for (int k = 0; k < 4; ++k)  t4[k]  = t2[k >> 1]  * ((k & 1) ? v[1] : 1.0f - v[1]);
        #pragma unroll
        for (int k = 0; k < 8; ++k)  t8[k]  = t4[k >> 1]  * ((k & 1) ? v[2] : 1.0f - v[2]);
        #pragma unroll
        for (int k = 0; k < 16; ++k) t16[k] = t8[k >> 1]  * ((k & 1) ? v[3] : 1.0f - v[3]);
        #pragma unroll
        for (int k = 0; k < 32; ++k) hi[k]  = t16[k >> 1] * ((k & 1) ? v[4] : 1.0f - v[4]);
    }
    {
        float t2[2], t4[4], t8[8], t16[16];
        t2[0] = 1.0f - v[5]; t2[1] = v[5];
        #pragma unroll
        for (int k = 0; k < 4; ++k)  t4[k]  = t2[k >> 1]  * ((k & 1) ? v[6] : 1.0f - v[6]);
        #pragma unroll
        for (int k = 0; k < 8; ++k)  t8[k]  = t4[k >> 1]  * ((k & 1) ? v[7] : 1.0f - v[7]);
        #pragma unroll
        for (int k = 0; k < 16; ++k) t16[k] = t8[k >> 1]  * ((k & 1) ? v[8] : 1.0f - v[8]);
        #pragma unroll
        for (int k = 0; k < 32; ++k) lo[k]  = t16[k >> 1] * ((k & 1) ? v[9] : 1.0f - v[9]);
    }

    // stage to LDS (stride 33: bank = (tid + k) % 32 -> 2 lanes/bank, free)
    #pragma unroll
    for (int k = 0; k < 32; ++k) Phi_s[tid * STRIDE + k] = hi[k];
    #pragma unroll
    for (int k = 0; k < 32; ++k) Plo_s[tid * STRIDE + k] = lo[k];

    __syncthreads();

    // Phase 2: C[32][32] += Phi^T Plo over the batch.
    // 64 lanes = 8x8 grid of 4x4 register tiles (covers all 1024 entries).
    // Wave w handles rows r == w (mod 2).
    const int wave = tid >> 6;
    const int lane = tid & 63;
    const int i0 = (lane >> 3) * 4;
    const int j0 = (lane & 7) * 4;

    float c[4][4];
    #pragma unroll
    for (int ii = 0; ii < 4; ++ii)
        #pragma unroll
        for (int jj = 0; jj < 4; ++jj) c[ii][jj] = 0.0f;

    for (int t = 0; t < BATCH / 2; ++t) {
        const int r = t * 2 + wave;
        const int base = r * STRIDE;
        float ph[4], pl[4];
        #pragma unroll
        for (int k = 0; k < 4; ++k) ph[k] = Phi_s[base + i0 + k];
        #pragma unroll
        for (int k = 0; k < 4; ++k) pl[k] = Plo_s[base + j0 + k];
        #pragma unroll
        for (int ii = 0; ii < 4; ++ii)
            #pragma unroll
            for (int jj = 0; jj < 4; ++jj)
                c[ii][jj] = fmaf(ph[ii], pl[jj], c[ii][jj]);
    }

    // block-level reduce across the 2 waves
    #pragma unroll
    for (int ii = 0; ii < 4; ++ii)
        #pragma unroll
        for (int jj = 0; jj < 4; ++jj)
            atomicAdd(&C_lds[(i0 + ii) * 32 + (j0 + jj)], c[ii][jj]);

    __syncthreads();

    // one global atomic pass per block
    #pragma unroll
    for (int k = 0; k < NBINS / BATCH; ++k) {
        const int e = tid + k * BATCH;
        atomicAdd(&gC[e], C_lds[e]);
    }
}

__global__ __launch_bounds__(256) void finalize_kernel(const float* __restrict__ gC,
                                                       float* __restrict__ out,
                                                       float invB)
{
    __shared__ float red[4];
    const int tid = threadIdx.x;
    float s = 0.0f;
    #pragma unroll
    for (int k = 0; k < 4; ++k) {
        const float p  = gC[tid * 4 + k] * invB;
        const float ps = fmaxf(p, 1e-12f);
        s += p * log2f(ps);   // out = sum p * log2(clip(p)) = -joint_h
    }
    #pragma unroll
    for (int off = 32; off > 0; off >>= 1) s += __shfl_down(s, off);
    if ((tid & 63) == 0) red[tid >> 6] = s;
    __syncthreads();
    if (tid == 0) out[0] = red[0] + red[1] + red[2] + red[3];
}

extern "C" void kernel_launch(void* const* d_in, const int* in_sizes, int n_in,
                              void* d_out, int out_size, void* d_ws, size_t ws_size,
                              hipStream_t stream)
{
    const float* act = (const float*)d_in[0];
    const int rows = in_sizes[0] / 10;   // B = 131072
    float* gC = (float*)d_ws;            // 1024-float accumulator

    // d_ws is poisoned (0xAA) and never re-poisoned between replays: zero it
    // every call (stream op -> graph-capture safe).
    hipMemsetAsync(gC, 0, NBINS * sizeof(float), stream);

    const int grid = (rows + BATCH - 1) / BATCH;   // 1024 blocks
    hist_kernel<<<grid, 128, 0, stream>>>(act, gC, rows);
    finalize_kernel<<<1, 256, 0, stream>>>(gC, (float*)d_out, 1.0f / (float)rows);
}